// Round 6
// baseline (124.518 us; speedup 1.0000x reference)
//
#include <hip/hip_runtime.h>

typedef __attribute__((ext_vector_type(8))) short short8;
typedef __attribute__((ext_vector_type(4))) float f32x4;
typedef __attribute__((ext_vector_type(16))) float f32x16;

#define B_ 8
#define T_ 128
#define N_ 170
#define F_ 64
#define ROWSTRIDE (N_ * F_) /* 10880 */

union U4 { unsigned u[4]; short8 s; };

__device__ __forceinline__ unsigned short f2bf(float f) {
    union { float f; unsigned u; } v; v.f = f;
    unsigned r = v.u + 0x7fffu + ((v.u >> 16) & 1u);
    return (unsigned short)(r >> 16);
}
// pack two f32 -> dword of 2 bf16 (lo = first operand), RNE
__device__ __forceinline__ unsigned cvtpk(float lo, float hi) {
    unsigned d;
    asm("v_cvt_pk_bf16_f32 %0, %1, %2" : "=v"(d) : "v"(lo), "v"(hi));
    return d;
}
// XOR-swizzled byte offsets (row-stride 128B / 256B)
__device__ __forceinline__ int swz128(int row, int byteInRow) {
    return row * 128 + (byteInRow ^ ((row & 7) << 4));
}
__device__ __forceinline__ int swz256(int row, int byteInRow) {
    return row * 256 + (byteInRow ^ ((row & 15) << 4));
}
// A/B fragment (16x16x32): lane -> row (l&15)+row0, k = 8*(l>>4)+e
__device__ __forceinline__ short8 ldfrag16(const char* base, int row0, int kbyte, int lane) {
    int row = row0 + (lane & 15);
    return *(const short8*)(base + swz128(row, kbyte + ((lane >> 4) << 4)));
}
__device__ __forceinline__ short8 ldfrag16w(const char* base, int row0, int kbyte, int lane) {
    int row = row0 + (lane & 15);
    return *(const short8*)(base + swz256(row, kbyte + ((lane >> 4) << 4)));
}
// B fragment (32x32x16): lane -> row (l&31)+row0, k = 8*(l>>5)+e
__device__ __forceinline__ short8 ldfrag32(const char* base, int row0, int colbyte, int lane) {
    int row = row0 + (lane & 31);
    return *(const short8*)(base + swz128(row, colbyte + ((lane >> 5) << 4)));
}
// weight B-fragment from pre-transposed bf16 table wT[j][k] (k-major)
__device__ __forceinline__ short8 wfragT(const unsigned short* __restrict__ wT, int nt, int kc, int lane) {
    int j  = nt * 16 + (lane & 15);
    int k0 = kc * 32 + ((lane >> 4) & 3) * 8;
    return *(const short8*)(wT + j * 64 + k0);
}
__device__ __forceinline__ f32x4 zero4() {
    f32x4 v = {0.f, 0.f, 0.f, 0.f};
    return v;
}
__device__ __forceinline__ f32x16 zero16() {
    f32x16 v = {0.f, 0.f, 0.f, 0.f, 0.f, 0.f, 0.f, 0.f,
                0.f, 0.f, 0.f, 0.f, 0.f, 0.f, 0.f, 0.f};
    return v;
}

// LayerNorm over 64 features spread as [nt(4) in-lane] x [16 lanes (l&15)]
__device__ __forceinline__ void ln64(const float (&z)[2][4][4], float (&o)[2][4][4]) {
#pragma unroll
    for (int mi = 0; mi < 2; ++mi)
#pragma unroll
    for (int r = 0; r < 4; ++r) {
        float s = z[mi][0][r] + z[mi][1][r] + z[mi][2][r] + z[mi][3][r];
        s += __shfl_xor(s, 1); s += __shfl_xor(s, 2);
        s += __shfl_xor(s, 4); s += __shfl_xor(s, 8);
        float mean = s * 0.015625f;
        float d[4]; float q = 0.f;
#pragma unroll
        for (int nt = 0; nt < 4; ++nt) { d[nt] = z[mi][nt][r] - mean; q += d[nt] * d[nt]; }
        q += __shfl_xor(q, 1); q += __shfl_xor(q, 2);
        q += __shfl_xor(q, 4); q += __shfl_xor(q, 8);
        float rstd = __builtin_amdgcn_rsqf(q * 0.015625f + 1e-5f);
#pragma unroll
        for (int nt = 0; nt < 4; ++nt) o[mi][nt][r] = d[nt] * rstd;
    }
}

// prologue: ws[w][j][k] = bf16(W_w[k][j]) — transposed k-major bf16 weights
__global__ void prep_weights(const float* __restrict__ Wq, const float* __restrict__ Wk,
                             const float* __restrict__ Wv, const float* __restrict__ Wo,
                             const float* __restrict__ Wf1, const float* __restrict__ Wf2,
                             unsigned short* __restrict__ ws) {
    const float* Ws[6] = {Wq, Wk, Wv, Wo, Wf1, Wf2};
    const float* W = Ws[blockIdx.x];
    unsigned short* o = ws + blockIdx.x * 4096;
#pragma unroll
    for (int i = 0; i < 16; ++i) {
        int idx = i * 256 + threadIdx.x;
        int j = idx >> 6, k = idx & 63;
        o[idx] = f2bf(W[k * 64 + j]);
    }
}

__global__ __launch_bounds__(256, 3)
void ta_fused(const float* __restrict__ x, const float* __restrict__ te,
              const unsigned short* __restrict__ wT,
              const float* __restrict__ bq, const float* __restrict__ bk,
              const float* __restrict__ bv, const float* __restrict__ bo,
              const float* __restrict__ bf1, const float* __restrict__ bf2,
              float* __restrict__ out)
{
    __shared__ __align__(16) char sQb[16384];   // Q -> val
    __shared__ __align__(16) char sKb[16384];   // K -> h1
    __shared__ __align__(16) char sVO[16384];   // V^T (swz256) -> attn-out O (swz128)

    const int tid  = threadIdx.x;
    const int lane = tid & 63;
    const int wv   = tid >> 6;
    const int lam  = lane & 15;
    const int g    = (lane >> 4) & 3;
    const int bid  = blockIdx.x;
    const int b    = bid / N_;
    const int n    = bid - b * N_;
    const long long base = ((long long)b * T_ * N_ + n) * F_;
    const int t0w = wv * 32;
    const int lg4 = g;

    // ---------------- P0: X = x + te, straight into registers ----------------
    // A-fragments for P1 (wave-local rows) + C-layout residual copy for P3.
    short8 ax[2][2];
    float xres[2][4][4];
#pragma unroll
    for (int mi = 0; mi < 2; ++mi) {
        const float* xr = x  + base + (long long)(t0w + mi * 16 + lam) * ROWSTRIDE;
        const float* tr = te + base + (long long)(t0w + mi * 16 + lam) * ROWSTRIDE;
#pragma unroll
        for (int kc = 0; kc < 2; ++kc) {
            int f0 = kc * 32 + g * 8;
            float4 a0 = *(const float4*)(xr + f0);
            float4 a1 = *(const float4*)(xr + f0 + 4);
            float4 c0 = *(const float4*)(tr + f0);
            float4 c1 = *(const float4*)(tr + f0 + 4);
            U4 u;
            u.u[0] = cvtpk(a0.x + c0.x, a0.y + c0.y);
            u.u[1] = cvtpk(a0.z + c0.z, a0.w + c0.w);
            u.u[2] = cvtpk(a1.x + c1.x, a1.y + c1.y);
            u.u[3] = cvtpk(a1.z + c1.z, a1.w + c1.w);
            ax[mi][kc] = u.s;
        }
#pragma unroll
        for (int nt = 0; nt < 4; ++nt)
#pragma unroll
        for (int r = 0; r < 4; ++r) {
            long long off = base + (long long)(t0w + mi * 16 + g * 4 + r) * ROWSTRIDE + nt * 16 + lam;
            xres[mi][nt][r] = x[off] + te[off];
        }
    }

    // ---------------- P1: Q,K,V projections (this wave's 32 rows) ----------------
    {
        const float* bp[3] = {bq, bk, bv};
#pragma unroll
        for (int w = 0; w < 3; ++w) {
            const unsigned short* wTp = wT + w * 4096;
            short8 bw[4][2]; float bias[4];
#pragma unroll
            for (int nt = 0; nt < 4; ++nt) {
                bw[nt][0] = wfragT(wTp, nt, 0, lane);
                bw[nt][1] = wfragT(wTp, nt, 1, lane);
                bias[nt]  = bp[w][nt * 16 + lam];
            }
            f32x4 acc[2][4];
#pragma unroll
            for (int mi = 0; mi < 2; ++mi)
#pragma unroll
            for (int nt = 0; nt < 4; ++nt) acc[mi][nt] = zero4();
#pragma unroll
            for (int kc = 0; kc < 2; ++kc)
#pragma unroll
            for (int mi = 0; mi < 2; ++mi)
#pragma unroll
            for (int nt = 0; nt < 4; ++nt)
                acc[mi][nt] = __builtin_amdgcn_mfma_f32_16x16x32_bf16(ax[mi][kc], bw[nt][kc], acc[mi][nt], 0, 0, 0);

            if (w < 2) {
                char* dst = (w == 0) ? sQb : sKb;
#pragma unroll
                for (int mi = 0; mi < 2; ++mi)
#pragma unroll
                for (int nt = 0; nt < 4; ++nt)
#pragma unroll
                for (int r = 0; r < 4; ++r) {
                    int t = t0w + mi * 16 + lg4 * 4 + r;
                    int f = nt * 16 + lam;
                    *(unsigned short*)(dst + swz128(t, f * 2)) = f2bf(acc[mi][nt][r] + bias[nt]);
                }
            } else { // V -> transposed sVO[f][t] (swz256), 4 consecutive t per b64
#pragma unroll
                for (int mi = 0; mi < 2; ++mi)
#pragma unroll
                for (int nt = 0; nt < 4; ++nt) {
                    int f   = nt * 16 + lam;
                    int tb0 = t0w + mi * 16 + lg4 * 4;
                    unsigned d0 = cvtpk(acc[mi][nt][0] + bias[nt], acc[mi][nt][1] + bias[nt]);
                    unsigned d1 = cvtpk(acc[mi][nt][2] + bias[nt], acc[mi][nt][3] + bias[nt]);
                    unsigned long long pkv = (unsigned long long)d0 | ((unsigned long long)d1 << 32);
                    *(unsigned long long*)(sVO + swz256(f, tb0 * 2)) = pkv;
                }
            }
        }
    }
    __syncthreads();

    // ---------------- P2: attention, head = wv ----------------
    {
        const int h    = wv;
        const int colb = h * 32;
        short8 vf[4], kfc[4];
#pragma unroll
        for (int sb = 0; sb < 4; ++sb) {
            vf[sb]  = ldfrag16w(sVO, h * 16, sb * 64, lane);
            kfc[sb] = ldfrag32(sKb, sb * 32, colb, lane);
        }
        __syncthreads();   // V^T fully register-cached; sVO free for O

        const int tcol = lane & 31;
        const int hi4  = (lane >> 5) * 4;
#pragma unroll
        for (int tb = 0; tb < 4; ++tb) {
            short8 qf = ldfrag32(sQb, tb * 32, colb, lane);
            f32x16 sacc[4];
#pragma unroll
            for (int sb = 0; sb <= tb; ++sb)
                sacc[sb] = __builtin_amdgcn_mfma_f32_32x32x16_bf16(kfc[sb], qf, zero16(), 0, 0, 0);
            // causal mask on diagonal tile
#pragma unroll
            for (int r = 0; r < 16; ++r) {
                int srow = (r & 3) + 8 * (r >> 2) + hi4;
                if (srow > tcol) sacc[tb][r] = -3.0e38f;
            }
            float m = -3.0e38f;
#pragma unroll
            for (int sb = 0; sb <= tb; ++sb)
#pragma unroll
                for (int r = 0; r < 16; ++r) m = fmaxf(m, sacc[sb][r]);
            m = fmaxf(m, __shfl_xor(m, 32));
            float sum = 0.f;
#pragma unroll
            for (int sb = 0; sb <= tb; ++sb)
#pragma unroll
                for (int r = 0; r < 16; ++r) {
                    float p = __expf((sacc[sb][r] - m) * 0.25f); // 1/sqrt(D)=0.25
                    sacc[sb][r] = p; sum += p;
                }
            sum += __shfl_xor(sum, 32);
            float rs = __builtin_amdgcn_rcpf(sum);

            // PV with in-register P->A-fragment transpose (cvt_pk + permlane swaps)
            f32x4 oacc[2];
            oacc[0] = zero4(); oacc[1] = zero4();
#pragma unroll
            for (int sb = 0; sb <= tb; ++sb) {
                float ps[16];
#pragma unroll
                for (int r = 0; r < 16; ++r) ps[r] = sacc[sb][r] * rs;
                unsigned a0 = cvtpk(ps[0],  ps[1]);
                unsigned a1 = cvtpk(ps[4],  ps[5]);
                unsigned a2 = cvtpk(ps[8],  ps[9]);
                unsigned a3 = cvtpk(ps[12], ps[13]);
                unsigned b0 = cvtpk(ps[2],  ps[3]);
                unsigned b1 = cvtpk(ps[6],  ps[7]);
                unsigned b2 = cvtpk(ps[10], ps[11]);
                unsigned b3 = cvtpk(ps[14], ps[15]);
                asm("v_permlane32_swap_b32 %0, %1" : "+v"(a0), "+v"(a2));
                asm("v_permlane32_swap_b32 %0, %1" : "+v"(a1), "+v"(a3));
                asm("v_permlane16_swap_b32 %0, %1" : "+v"(a0), "+v"(a1));
                asm("v_permlane16_swap_b32 %0, %1" : "+v"(a2), "+v"(a3));
                asm("v_permlane32_swap_b32 %0, %1" : "+v"(b0), "+v"(b2));
                asm("v_permlane32_swap_b32 %0, %1" : "+v"(b1), "+v"(b3));
                asm("v_permlane16_swap_b32 %0, %1" : "+v"(b0), "+v"(b1));
                asm("v_permlane16_swap_b32 %0, %1" : "+v"(b2), "+v"(b3));
                U4 F0, F1;
                F0.u[0] = a0; F0.u[1] = b0; F0.u[2] = a2; F0.u[3] = b2; // t-local 0..15
                F1.u[0] = a1; F1.u[1] = b1; F1.u[2] = a3; F1.u[3] = b3; // t-local 16..31
                oacc[0] = __builtin_amdgcn_mfma_f32_16x16x32_bf16(F0.s, vf[sb], oacc[0], 0, 0, 0);
                oacc[1] = __builtin_amdgcn_mfma_f32_16x16x32_bf16(F1.s, vf[sb], oacc[1], 0, 0, 0);
            }
#pragma unroll
            for (int mi = 0; mi < 2; ++mi)
#pragma unroll
            for (int r = 0; r < 4; ++r) {
                int t = tb * 32 + mi * 16 + lg4 * 4 + r;
                int f = h * 16 + lam;
                *(unsigned short*)(sVO + swz128(t, f * 2)) = f2bf(oacc[mi][r]);
            }
        }
    }
    __syncthreads();

    // ---------------- P3: Wo + residual + LN ----------------
    float val[2][4][4];
    {
        short8 af[2][2];
#pragma unroll
        for (int mi = 0; mi < 2; ++mi)
#pragma unroll
        for (int kc = 0; kc < 2; ++kc) af[mi][kc] = ldfrag16(sVO, t0w + mi * 16, kc * 64, lane);
        const unsigned short* wTp = wT + 3 * 4096;
        short8 bwf[4][2]; float bias[4];
#pragma unroll
        for (int nt = 0; nt < 4; ++nt) {
            bwf[nt][0] = wfragT(wTp, nt, 0, lane);
            bwf[nt][1] = wfragT(wTp, nt, 1, lane);
            bias[nt]   = bo[nt * 16 + lam];
        }
        f32x4 acc[2][4];
#pragma unroll
        for (int mi = 0; mi < 2; ++mi)
#pragma unroll
        for (int nt = 0; nt < 4; ++nt) acc[mi][nt] = zero4();
#pragma unroll
        for (int kc = 0; kc < 2; ++kc)
#pragma unroll
        for (int mi = 0; mi < 2; ++mi)
#pragma unroll
        for (int nt = 0; nt < 4; ++nt)
            acc[mi][nt] = __builtin_amdgcn_mfma_f32_16x16x32_bf16(af[mi][kc], bwf[nt][kc], acc[mi][nt], 0, 0, 0);
        float z[2][4][4];
#pragma unroll
        for (int mi = 0; mi < 2; ++mi)
#pragma unroll
        for (int nt = 0; nt < 4; ++nt)
#pragma unroll
        for (int r = 0; r < 4; ++r)
            z[mi][nt][r] = acc[mi][nt][r] + bias[nt] + xres[mi][nt][r];
        ln64(z, val);
#pragma unroll
        for (int mi = 0; mi < 2; ++mi)
#pragma unroll
        for (int nt = 0; nt < 4; ++nt)
#pragma unroll
        for (int r = 0; r < 4; ++r) {
            int t = t0w + mi * 16 + lg4 * 4 + r;
            int f = nt * 16 + lam;
            *(unsigned short*)(sQb + swz128(t, f * 2)) = f2bf(val[mi][nt][r]); // val -> sQb
        }
    }
    // rows are wave-private from here on: no barriers needed

    // ---------------- P4: FF1 + ReLU ----------------
    {
        short8 af[2][2];
#pragma unroll
        for (int mi = 0; mi < 2; ++mi)
#pragma unroll
        for (int kc = 0; kc < 2; ++kc) af[mi][kc] = ldfrag16(sQb, t0w + mi * 16, kc * 64, lane);
        const unsigned short* wTp = wT + 4 * 4096;
        short8 bwf[4][2]; float bias[4];
#pragma unroll
        for (int nt = 0; nt < 4; ++nt) {
            bwf[nt][0] = wfragT(wTp, nt, 0, lane);
            bwf[nt][1] = wfragT(wTp, nt, 1, lane);
            bias[nt]   = bf1[nt * 16 + lam];
        }
        f32x4 acc[2][4];
#pragma unroll
        for (int mi = 0; mi < 2; ++mi)
#pragma unroll
        for (int nt = 0; nt < 4; ++nt) acc[mi][nt] = zero4();
#pragma unroll
        for (int kc = 0; kc < 2; ++kc)
#pragma unroll
        for (int mi = 0; mi < 2; ++mi)
#pragma unroll
        for (int nt = 0; nt < 4; ++nt)
            acc[mi][nt] = __builtin_amdgcn_mfma_f32_16x16x32_bf16(af[mi][kc], bwf[nt][kc], acc[mi][nt], 0, 0, 0);
#pragma unroll
        for (int mi = 0; mi < 2; ++mi)
#pragma unroll
        for (int nt = 0; nt < 4; ++nt)
#pragma unroll
        for (int r = 0; r < 4; ++r) {
            int t = t0w + mi * 16 + lg4 * 4 + r;
            int f = nt * 16 + lam;
            *(unsigned short*)(sKb + swz128(t, f * 2)) = f2bf(fmaxf(acc[mi][nt][r] + bias[nt], 0.f)); // h1 -> sKb
        }
    }

    // ---------------- P5: FF2 + residual + LN + store ----------------
    {
        short8 af[2][2];
#pragma unroll
        for (int mi = 0; mi < 2; ++mi)
#pragma unroll
        for (int kc = 0; kc < 2; ++kc) af[mi][kc] = ldfrag16(sKb, t0w + mi * 16, kc * 64, lane);
        const unsigned short* wTp = wT + 5 * 4096;
        short8 bwf[4][2]; float bias[4];
#pragma unroll
        for (int nt = 0; nt < 4; ++nt) {
            bwf[nt][0] = wfragT(wTp, nt, 0, lane);
            bwf[nt][1] = wfragT(wTp, nt, 1, lane);
            bias[nt]   = bf2[nt * 16 + lam];
        }
        f32x4 acc[2][4];
#pragma unroll
        for (int mi = 0; mi < 2; ++mi)
#pragma unroll
        for (int nt = 0; nt < 4; ++nt) acc[mi][nt] = zero4();
#pragma unroll
        for (int kc = 0; kc < 2; ++kc)
#pragma unroll
        for (int mi = 0; mi < 2; ++mi)
#pragma unroll
        for (int nt = 0; nt < 4; ++nt)
            acc[mi][nt] = __builtin_amdgcn_mfma_f32_16x16x32_bf16(af[mi][kc], bwf[nt][kc], acc[mi][nt], 0, 0, 0);
        float z[2][4][4], res[2][4][4];
#pragma unroll
        for (int mi = 0; mi < 2; ++mi)
#pragma unroll
        for (int nt = 0; nt < 4; ++nt)
#pragma unroll
        for (int r = 0; r < 4; ++r)
            z[mi][nt][r] = acc[mi][nt][r] + bias[nt] + val[mi][nt][r];
        ln64(z, res);
#pragma unroll
        for (int mi = 0; mi < 2; ++mi)
#pragma unroll
        for (int nt = 0; nt < 4; ++nt)
#pragma unroll
        for (int r = 0; r < 4; ++r) {
            int t = t0w + mi * 16 + lg4 * 4 + r;
            int f = nt * 16 + lam;
            out[base + (long long)t * ROWSTRIDE + f] = res[mi][nt][r];
        }
    }
}

extern "C" void kernel_launch(void* const* d_in, const int* in_sizes, int n_in,
                              void* d_out, int out_size, void* d_ws, size_t ws_size,
                              hipStream_t stream) {
    const float* x   = (const float*)d_in[0];
    const float* te  = (const float*)d_in[1];
    const float* Wq  = (const float*)d_in[2];
    const float* bq  = (const float*)d_in[3];
    const float* Wk  = (const float*)d_in[4];
    const float* bk  = (const float*)d_in[5];
    const float* Wv  = (const float*)d_in[6];
    const float* bv  = (const float*)d_in[7];
    const float* Wo  = (const float*)d_in[8];
    const float* bo  = (const float*)d_in[9];
    const float* Wf1 = (const float*)d_in[10];
    const float* bf1 = (const float*)d_in[11];
    const float* Wf2 = (const float*)d_in[12];
    const float* bf2 = (const float*)d_in[13];
    unsigned short* wsT = (unsigned short*)d_ws;

    prep_weights<<<dim3(6), dim3(256), 0, stream>>>(Wq, Wk, Wv, Wo, Wf1, Wf2, wsT);
    ta_fused<<<dim3(B_ * N_), dim3(256), 0, stream>>>(
        x, te, wsT, bq, bk, bv, bo, bf1, bf2, (float*)d_out);
}

// Round 7
// 73.369 us; speedup vs baseline: 1.6971x; 1.6971x over previous
//
#include <hip/hip_runtime.h>

typedef __attribute__((ext_vector_type(8))) short short8;
typedef __attribute__((ext_vector_type(4))) float f32x4;
typedef __attribute__((ext_vector_type(16))) float f32x16;

#define B_ 8
#define T_ 128
#define N_ 170
#define F_ 64
#define ROWSTRIDE (N_ * F_) /* 10880 */

union U4 { unsigned u[4]; short8 s; };

__device__ __forceinline__ unsigned short f2bf(float f) {
    union { float f; unsigned u; } v; v.f = f;
    unsigned r = v.u + 0x7fffu + ((v.u >> 16) & 1u);
    return (unsigned short)(r >> 16);
}
// pack two f32 -> dword of 2 bf16 (lo = first operand), RNE
__device__ __forceinline__ unsigned cvtpk(float lo, float hi) {
    unsigned d;
    asm("v_cvt_pk_bf16_f32 %0, %1, %2" : "=v"(d) : "v"(lo), "v"(hi));
    return d;
}
// XOR-swizzled byte offsets (row-stride 128B / 256B)
__device__ __forceinline__ int swz128(int row, int byteInRow) {
    return row * 128 + (byteInRow ^ ((row & 7) << 4));
}
__device__ __forceinline__ int swz256(int row, int byteInRow) {
    return row * 256 + (byteInRow ^ ((row & 15) << 4));
}
// A/B fragment (16x16x32): lane -> row (l&15)+row0, k = 8*(l>>4)+e
__device__ __forceinline__ short8 ldfrag16(const char* base, int row0, int kbyte, int lane) {
    int row = row0 + (lane & 15);
    return *(const short8*)(base + swz128(row, kbyte + ((lane >> 4) << 4)));
}
__device__ __forceinline__ short8 ldfrag16w(const char* base, int row0, int kbyte, int lane) {
    int row = row0 + (lane & 15);
    return *(const short8*)(base + swz256(row, kbyte + ((lane >> 4) << 4)));
}
// B/A fragment (32x32x16): lane -> row (l&31)+row0, k = 8*(l>>5)+e
__device__ __forceinline__ short8 ldfrag32(const char* base, int row0, int colbyte, int lane) {
    int row = row0 + (lane & 31);
    return *(const short8*)(base + swz128(row, colbyte + ((lane >> 5) << 4)));
}
// weight B-fragment from pre-transposed bf16 table wT[j][k] (k-major)
__device__ __forceinline__ short8 wfragT(const unsigned short* __restrict__ wT, int nt, int kc, int lane) {
    int j  = nt * 16 + (lane & 15);
    int k0 = kc * 32 + ((lane >> 4) & 3) * 8;
    return *(const short8*)(wT + j * 64 + k0);
}
__device__ __forceinline__ f32x4 zero4() {
    f32x4 v = {0.f, 0.f, 0.f, 0.f};
    return v;
}
__device__ __forceinline__ f32x16 zero16() {
    f32x16 v = {0.f, 0.f, 0.f, 0.f, 0.f, 0.f, 0.f, 0.f,
                0.f, 0.f, 0.f, 0.f, 0.f, 0.f, 0.f, 0.f};
    return v;
}

// LayerNorm over 64 features spread as [nt(4) in-lane] x [16 lanes (l&15)]
__device__ __forceinline__ void ln64(const float (&z)[2][4][4], float (&o)[2][4][4]) {
#pragma unroll
    for (int mi = 0; mi < 2; ++mi)
#pragma unroll
    for (int r = 0; r < 4; ++r) {
        float s = z[mi][0][r] + z[mi][1][r] + z[mi][2][r] + z[mi][3][r];
        s += __shfl_xor(s, 1); s += __shfl_xor(s, 2);
        s += __shfl_xor(s, 4); s += __shfl_xor(s, 8);
        float mean = s * 0.015625f;
        float d[4]; float q = 0.f;
#pragma unroll
        for (int nt = 0; nt < 4; ++nt) { d[nt] = z[mi][nt][r] - mean; q += d[nt] * d[nt]; }
        q += __shfl_xor(q, 1); q += __shfl_xor(q, 2);
        q += __shfl_xor(q, 4); q += __shfl_xor(q, 8);
        float rstd = __builtin_amdgcn_rsqf(q * 0.015625f + 1e-5f);
#pragma unroll
        for (int nt = 0; nt < 4; ++nt) o[mi][nt][r] = d[nt] * rstd;
    }
}

// prologue: ws[w][j][k] = bf16(W_w[k][j]) — transposed k-major bf16 weights
__global__ void prep_weights(const float* __restrict__ Wq, const float* __restrict__ Wk,
                             const float* __restrict__ Wv, const float* __restrict__ Wo,
                             const float* __restrict__ Wf1, const float* __restrict__ Wf2,
                             unsigned short* __restrict__ ws) {
    const float* Ws[6] = {Wq, Wk, Wv, Wo, Wf1, Wf2};
    const float* W = Ws[blockIdx.x];
    unsigned short* o = ws + blockIdx.x * 4096;
#pragma unroll
    for (int i = 0; i < 16; ++i) {
        int idx = i * 256 + threadIdx.x;
        int j = idx >> 6, k = idx & 63;
        o[idx] = f2bf(W[k * 64 + j]);
    }
}

__global__ __launch_bounds__(256, 3)
void ta_fused(const float* __restrict__ x, const float* __restrict__ te,
              const unsigned short* __restrict__ wT,
              const float* __restrict__ bq, const float* __restrict__ bk,
              const float* __restrict__ bv, const float* __restrict__ bo,
              const float* __restrict__ bf1, const float* __restrict__ bf2,
              float* __restrict__ out)
{
    __shared__ __align__(16) char sKb[16384];   // K [128][64] swz128 (shared, read-only after barrier)
    __shared__ __align__(16) char sVt[16384];   // V^T [64][128] swz256 (shared, read-only after barrier)
    __shared__ __align__(16) char sBn[16384];   // 4x 4KB wave-private bounce: Q -> O -> val -> h1

    const int tid  = threadIdx.x;
    const int lane = tid & 63;
    const int wv   = tid >> 6;
    const int lam  = lane & 15;
    const int g    = (lane >> 4) & 3;
    const int bid  = blockIdx.x;
    const int b    = bid / N_;
    const int n    = bid - b * N_;
    const long long base = ((long long)b * T_ * N_ + n) * F_;
    const int t0w = wv * 32;
    char* myb = sBn + wv * 4096;   // this wave's 32x64 bf16 bounce tile (local rows 0..31)

    // ---------------- P0: X = x + te straight into A-fragments (global, coalesced) ----------------
    short8 ax[2][2];   // [mi][kc]: lane row t0w+mi*16+(l&15), feats kc*32+g*8..+7
#pragma unroll
    for (int mi = 0; mi < 2; ++mi) {
        const float* xr = x  + base + (long long)(t0w + mi * 16 + lam) * ROWSTRIDE;
        const float* tr = te + base + (long long)(t0w + mi * 16 + lam) * ROWSTRIDE;
#pragma unroll
        for (int kc = 0; kc < 2; ++kc) {
            int f0 = kc * 32 + g * 8;
            float4 a0 = *(const float4*)(xr + f0);
            float4 a1 = *(const float4*)(xr + f0 + 4);
            float4 c0 = *(const float4*)(tr + f0);
            float4 c1 = *(const float4*)(tr + f0 + 4);
            U4 u;
            u.u[0] = cvtpk(a0.x + c0.x, a0.y + c0.y);
            u.u[1] = cvtpk(a0.z + c0.z, a0.w + c0.w);
            u.u[2] = cvtpk(a1.x + c1.x, a1.y + c1.y);
            u.u[3] = cvtpk(a1.z + c1.z, a1.w + c1.w);
            ax[mi][kc] = u.s;
        }
    }

    // ---------------- P1: Q,K,V projections for this wave's 32 rows ----------------
    {
        const float* bp[3] = {bq, bk, bv};
#pragma unroll
        for (int w = 0; w < 3; ++w) {
            const unsigned short* wTp = wT + w * 4096;
            short8 bw[4][2]; float bias[4];
#pragma unroll
            for (int nt = 0; nt < 4; ++nt) {
                bw[nt][0] = wfragT(wTp, nt, 0, lane);
                bw[nt][1] = wfragT(wTp, nt, 1, lane);
                bias[nt]  = bp[w][nt * 16 + lam];
            }
            f32x4 acc[2][4];
#pragma unroll
            for (int mi = 0; mi < 2; ++mi)
#pragma unroll
            for (int nt = 0; nt < 4; ++nt) acc[mi][nt] = zero4();
#pragma unroll
            for (int kc = 0; kc < 2; ++kc)
#pragma unroll
            for (int mi = 0; mi < 2; ++mi)
#pragma unroll
            for (int nt = 0; nt < 4; ++nt)
                acc[mi][nt] = __builtin_amdgcn_mfma_f32_16x16x32_bf16(ax[mi][kc], bw[nt][kc], acc[mi][nt], 0, 0, 0);

            if (w == 0) {        // Q -> wave-private bounce, LOCAL rows 0..31
#pragma unroll
                for (int mi = 0; mi < 2; ++mi)
#pragma unroll
                for (int nt = 0; nt < 4; ++nt)
#pragma unroll
                for (int r = 0; r < 4; ++r) {
                    int t = mi * 16 + g * 4 + r;
                    int f = nt * 16 + lam;
                    *(unsigned short*)(myb + swz128(t, f * 2)) = f2bf(acc[mi][nt][r] + bias[nt]);
                }
            } else if (w == 1) { // K -> shared sKb, global rows
#pragma unroll
                for (int mi = 0; mi < 2; ++mi)
#pragma unroll
                for (int nt = 0; nt < 4; ++nt)
#pragma unroll
                for (int r = 0; r < 4; ++r) {
                    int t = t0w + mi * 16 + g * 4 + r;
                    int f = nt * 16 + lam;
                    *(unsigned short*)(sKb + swz128(t, f * 2)) = f2bf(acc[mi][nt][r] + bias[nt]);
                }
            } else {             // V -> transposed sVt[f][t] (swz256), 4 consecutive t per b64
#pragma unroll
                for (int mi = 0; mi < 2; ++mi)
#pragma unroll
                for (int nt = 0; nt < 4; ++nt) {
                    int f   = nt * 16 + lam;
                    int tb0 = t0w + mi * 16 + g * 4;
                    unsigned d0 = cvtpk(acc[mi][nt][0] + bias[nt], acc[mi][nt][1] + bias[nt]);
                    unsigned d1 = cvtpk(acc[mi][nt][2] + bias[nt], acc[mi][nt][3] + bias[nt]);
                    unsigned long long pkv = (unsigned long long)d0 | ((unsigned long long)d1 << 32);
                    *(unsigned long long*)(sVt + swz256(f, tb0 * 2)) = pkv;
                }
            }
        }
    }
    __syncthreads();   // the ONLY barrier: K and V^T now valid for all waves

    // ---------------- P2: attention for this wave's 32 t-rows, looping all 4 heads ----------------
    {
        const int tcol = lane & 31;          // t-local owned by this lane (S^T column)
        const int hi4  = (lane >> 5) * 4;
        f32x4 oacc[4][2];
#pragma unroll
        for (int h = 0; h < 4; ++h) { oacc[h][0] = zero4(); oacc[h][1] = zero4(); }

#pragma unroll
        for (int h = 0; h < 4; ++h) {
            short8 qf = ldfrag32(myb, 0, h * 32, lane);   // B-frag of wave's own Q rows
            f32x16 sacc[4];
#pragma unroll
            for (int sb = 0; sb < 4; ++sb) {
                if (sb > wv) continue;       // causal: s-tiles 0..wv (wave-uniform)
                short8 kf = ldfrag32(sKb, sb * 32, h * 32, lane);
                sacc[sb] = __builtin_amdgcn_mfma_f32_32x32x16_bf16(kf, qf, zero16(), 0, 0, 0);
                if (sb == wv) {              // diagonal tile mask (static index)
#pragma unroll
                    for (int r = 0; r < 16; ++r) {
                        int srow = (r & 3) + 8 * (r >> 2) + hi4;
                        if (srow > tcol) sacc[sb][r] = -3.0e38f;
                    }
                }
            }
            float m = -3.0e38f;
#pragma unroll
            for (int sb = 0; sb < 4; ++sb) {
                if (sb > wv) continue;
#pragma unroll
                for (int r = 0; r < 16; ++r) m = fmaxf(m, sacc[sb][r]);
            }
            m = fmaxf(m, __shfl_xor(m, 32));
            float sum = 0.f;
#pragma unroll
            for (int sb = 0; sb < 4; ++sb) {
                if (sb > wv) continue;
#pragma unroll
                for (int r = 0; r < 16; ++r) {
                    float p = __expf((sacc[sb][r] - m) * 0.25f);   // 1/sqrt(D)=0.25
                    sacc[sb][r] = p; sum += p;
                }
            }
            sum += __shfl_xor(sum, 32);
            float rs = __builtin_amdgcn_rcpf(sum);

            // PV with in-register P->A-fragment transpose (R3-validated network)
#pragma unroll
            for (int sb = 0; sb < 4; ++sb) {
                if (sb > wv) continue;
                float ps[16];
#pragma unroll
                for (int r = 0; r < 16; ++r) ps[r] = sacc[sb][r] * rs;
                unsigned a0 = cvtpk(ps[0],  ps[1]);
                unsigned a1 = cvtpk(ps[4],  ps[5]);
                unsigned a2 = cvtpk(ps[8],  ps[9]);
                unsigned a3 = cvtpk(ps[12], ps[13]);
                unsigned b0 = cvtpk(ps[2],  ps[3]);
                unsigned b1 = cvtpk(ps[6],  ps[7]);
                unsigned b2 = cvtpk(ps[10], ps[11]);
                unsigned b3 = cvtpk(ps[14], ps[15]);
                asm("v_permlane32_swap_b32 %0, %1" : "+v"(a0), "+v"(a2));
                asm("v_permlane32_swap_b32 %0, %1" : "+v"(a1), "+v"(a3));
                asm("v_permlane16_swap_b32 %0, %1" : "+v"(a0), "+v"(a1));
                asm("v_permlane16_swap_b32 %0, %1" : "+v"(a2), "+v"(a3));
                asm("v_permlane32_swap_b32 %0, %1" : "+v"(b0), "+v"(b2));
                asm("v_permlane32_swap_b32 %0, %1" : "+v"(b1), "+v"(b3));
                asm("v_permlane16_swap_b32 %0, %1" : "+v"(b0), "+v"(b1));
                asm("v_permlane16_swap_b32 %0, %1" : "+v"(b2), "+v"(b3));
                U4 F0, F1;
                F0.u[0] = a0; F0.u[1] = b0; F0.u[2] = a2; F0.u[3] = b2; // t-local 0..15
                F1.u[0] = a1; F1.u[1] = b1; F1.u[2] = a3; F1.u[3] = b3; // t-local 16..31
                short8 vf = ldfrag16w(sVt, h * 16, sb * 64, lane);
                oacc[h][0] = __builtin_amdgcn_mfma_f32_16x16x32_bf16(F0.s, vf, oacc[h][0], 0, 0, 0);
                oacc[h][1] = __builtin_amdgcn_mfma_f32_16x16x32_bf16(F1.s, vf, oacc[h][1], 0, 0, 0);
            }
        }

        // O (all heads) -> wave-private bounce, LOCAL rows (overwrites Q; no barrier needed)
#pragma unroll
        for (int h = 0; h < 4; ++h)
#pragma unroll
        for (int mi = 0; mi < 2; ++mi)
#pragma unroll
        for (int r = 0; r < 4; ++r) {
            int t = mi * 16 + g * 4 + r;
            int f = h * 16 + lam;
            *(unsigned short*)(myb + swz128(t, f * 2)) = f2bf(oacc[h][mi][r]);
        }
    }
    // everything below is wave-private: ZERO barriers to the end

    // ---------------- P3: Wo + residual(X re-read) + LN ----------------
    float val[2][4][4];
    {
        short8 af[2][2];
#pragma unroll
        for (int mi = 0; mi < 2; ++mi)
#pragma unroll
        for (int kc = 0; kc < 2; ++kc) af[mi][kc] = ldfrag16(myb, mi * 16, kc * 64, lane);
        const unsigned short* wTp = wT + 3 * 4096;
        short8 bwf[4][2]; float bias[4];
#pragma unroll
        for (int nt = 0; nt < 4; ++nt) {
            bwf[nt][0] = wfragT(wTp, nt, 0, lane);
            bwf[nt][1] = wfragT(wTp, nt, 1, lane);
            bias[nt]   = bo[nt * 16 + lam];
        }
        f32x4 acc[2][4];
#pragma unroll
        for (int mi = 0; mi < 2; ++mi)
#pragma unroll
        for (int nt = 0; nt < 4; ++nt) acc[mi][nt] = zero4();
#pragma unroll
        for (int kc = 0; kc < 2; ++kc)
#pragma unroll
        for (int mi = 0; mi < 2; ++mi)
#pragma unroll
        for (int nt = 0; nt < 4; ++nt)
            acc[mi][nt] = __builtin_amdgcn_mfma_f32_16x16x32_bf16(af[mi][kc], bwf[nt][kc], acc[mi][nt], 0, 0, 0);
        float z[2][4][4];
#pragma unroll
        for (int mi = 0; mi < 2; ++mi)
#pragma unroll
        for (int nt = 0; nt < 4; ++nt)
#pragma unroll
        for (int r = 0; r < 4; ++r) {
            long long off = base + (long long)(t0w + mi * 16 + g * 4 + r) * ROWSTRIDE + nt * 16 + lam;
            z[mi][nt][r] = acc[mi][nt][r] + bias[nt] + x[off] + te[off];  // consumed immediately
        }
        ln64(z, val);
#pragma unroll
        for (int mi = 0; mi < 2; ++mi)
#pragma unroll
        for (int nt = 0; nt < 4; ++nt)
#pragma unroll
        for (int r = 0; r < 4; ++r) {
            int t = mi * 16 + g * 4 + r;
            int f = nt * 16 + lam;
            *(unsigned short*)(myb + swz128(t, f * 2)) = f2bf(val[mi][nt][r]); // val -> bounce
        }
    }

    // ---------------- P4: FF1 + ReLU ----------------
    {
        short8 af[2][2];
#pragma unroll
        for (int mi = 0; mi < 2; ++mi)
#pragma unroll
        for (int kc = 0; kc < 2; ++kc) af[mi][kc] = ldfrag16(myb, mi * 16, kc * 64, lane);
        const unsigned short* wTp = wT + 4 * 4096;
        short8 bwf[4][2]; float bias[4];
#pragma unroll
        for (int nt = 0; nt < 4; ++nt) {
            bwf[nt][0] = wfragT(wTp, nt, 0, lane);
            bwf[nt][1] = wfragT(wTp, nt, 1, lane);
            bias[nt]   = bf1[nt * 16 + lam];
        }
        f32x4 acc[2][4];
#pragma unroll
        for (int mi = 0; mi < 2; ++mi)
#pragma unroll
        for (int nt = 0; nt < 4; ++nt) acc[mi][nt] = zero4();
#pragma unroll
        for (int kc = 0; kc < 2; ++kc)
#pragma unroll
        for (int mi = 0; mi < 2; ++mi)
#pragma unroll
        for (int nt = 0; nt < 4; ++nt)
            acc[mi][nt] = __builtin_amdgcn_mfma_f32_16x16x32_bf16(af[mi][kc], bwf[nt][kc], acc[mi][nt], 0, 0, 0);
#pragma unroll
        for (int mi = 0; mi < 2; ++mi)
#pragma unroll
        for (int nt = 0; nt < 4; ++nt)
#pragma unroll
        for (int r = 0; r < 4; ++r) {
            int t = mi * 16 + g * 4 + r;
            int f = nt * 16 + lam;
            *(unsigned short*)(myb + swz128(t, f * 2)) = f2bf(fmaxf(acc[mi][nt][r] + bias[nt], 0.f)); // h1 -> bounce
        }
    }

    // ---------------- P5: FF2 + residual + LN + store ----------------
    {
        short8 af[2][2];
#pragma unroll
        for (int mi = 0; mi < 2; ++mi)
#pragma unroll
        for (int kc = 0; kc < 2; ++kc) af[mi][kc] = ldfrag16(myb, mi * 16, kc * 64, lane);
        const unsigned short* wTp = wT + 5 * 4096;
        short8 bwf[4][2]; float bias[4];
#pragma unroll
        for (int nt = 0; nt < 4; ++nt) {
            bwf[nt][0] = wfragT(wTp, nt, 0, lane);
            bwf[nt][1] = wfragT(wTp, nt, 1, lane);
            bias[nt]   = bf2[nt * 16 + lam];
        }
        f32x4 acc[2][4];
#pragma unroll
        for (int mi = 0; mi < 2; ++mi)
#pragma unroll
        for (int nt = 0; nt < 4; ++nt) acc[mi][nt] = zero4();
#pragma unroll
        for (int kc = 0; kc < 2; ++kc)
#pragma unroll
        for (int mi = 0; mi < 2; ++mi)
#pragma unroll
        for (int nt = 0; nt < 4; ++nt)
            acc[mi][nt] = __builtin_amdgcn_mfma_f32_16x16x32_bf16(af[mi][kc], bwf[nt][kc], acc[mi][nt], 0, 0, 0);
        float z[2][4][4], res[2][4][4];
#pragma unroll
        for (int mi = 0; mi < 2; ++mi)
#pragma unroll
        for (int nt = 0; nt < 4; ++nt)
#pragma unroll
        for (int r = 0; r < 4; ++r)
            z[mi][nt][r] = acc[mi][nt][r] + bias[nt] + val[mi][nt][r];
        ln64(z, res);
#pragma unroll
        for (int mi = 0; mi < 2; ++mi)
#pragma unroll
        for (int nt = 0; nt < 4; ++nt)
#pragma unroll
        for (int r = 0; r < 4; ++r) {
            int t = t0w + mi * 16 + g * 4 + r;
            int f = nt * 16 + lam;
            out[base + (long long)t * ROWSTRIDE + f] = res[mi][nt][r];
        }
    }
}

extern "C" void kernel_launch(void* const* d_in, const int* in_sizes, int n_in,
                              void* d_out, int out_size, void* d_ws, size_t ws_size,
                              hipStream_t stream) {
    const float* x   = (const float*)d_in[0];
    const float* te  = (const float*)d_in[1];
    const float* Wq  = (const float*)d_in[2];
    const float* bq  = (const float*)d_in[3];
    const float* Wk  = (const float*)d_in[4];
    const float* bk  = (const float*)d_in[5];
    const float* Wv  = (const float*)d_in[6];
    const float* bv  = (const float*)d_in[7];
    const float* Wo  = (const float*)d_in[8];
    const float* bo  = (const float*)d_in[9];
    const float* Wf1 = (const float*)d_in[10];
    const float* bf1 = (const float*)d_in[11];
    const float* Wf2 = (const float*)d_in[12];
    const float* bf2 = (const float*)d_in[13];
    unsigned short* wsT = (unsigned short*)d_ws;

    prep_weights<<<dim3(6), dim3(256), 0, stream>>>(Wq, Wk, Wv, Wo, Wf1, Wf2, wsT);
    ta_fused<<<dim3(B_ * N_), dim3(256), 0, stream>>>(
        x, te, wsT, bq, bk, bv, bo, bf1, bf2, (float*)d_out);
}